// Round 7
// baseline (40.198 us; speedup 1.0000x reference)
//
#include <hip/hip_runtime.h>

#define TT 4096
#define DD 256

typedef __attribute__((ext_vector_type(8))) short short8;
typedef __attribute__((ext_vector_type(4))) float f32x4;
typedef __attribute__((ext_vector_type(2))) unsigned int u32x2;
typedef __attribute__((ext_vector_type(4))) unsigned int u32x4;

__device__ __forceinline__ unsigned int f2bf(float f) {
    unsigned int u = __builtin_bit_cast(unsigned int, f);
    u += 0x7fffu + ((u >> 16) & 1u);          // RNE
    return u >> 16;
}

#define INV_E 0.36787944117144233f
#define LOG2R (-0.5307378454346229f)          // log2(exp(-1/e))

#define GLDS16(g, l) __builtin_amdgcn_global_load_lds(                         \
    (const __attribute__((address_space(1))) void*)(g),                        \
    (__attribute__((address_space(3))) void*)(l), 16, 0, 0)

// ---------------- kPre: W fp32 -> bf16 (once, 128 KB) ----------------
__global__ __launch_bounds__(256)
void kPre(const float* __restrict__ Win, unsigned short* __restrict__ Wbf) {
    int i = ((int)blockIdx.x * 256 + (int)threadIdx.x) * 4;
    float4 v = *(const float4*)(Win + i);
    u32x2 p;
    p.x = f2bf(v.x) | (f2bf(v.y) << 16);
    p.y = f2bf(v.z) | (f2bf(v.w) << 16);
    *(u32x2*)(Wbf + i) = p;
}

// ---- k1: zw[b][n][t] = w[t]*(x@W^T + b)[t][n], bf16, stored transposed ----
// 64 t-rows x 128 n-cols per block, K=256 in 4 chunks of 64.
__global__ __launch_bounds__(256, 3)
void k1(const float* __restrict__ x, const float* __restrict__ mask,
        const unsigned short* __restrict__ Wbf, const float* __restrict__ bin,
        unsigned short* __restrict__ zw)
{
    __shared__ union {
        struct {
            unsigned short xl[2][64][64];     // x chunk bf16, XOR-quarter swizzled (16 KB)
            unsigned short wl[2][128][64];    // W chunk bf16, glds linear dest (32 KB)
        } s;
        unsigned int T[128][36];              // epilogue transpose, 16B-aligned rows (18.4 KB)
    } U;

    const int tid = threadIdx.x;
    const int cpx = (int)gridDim.x >> 3;
    const int wg  = ((int)blockIdx.x & 7) * cpx + ((int)blockIdx.x >> 3);
    const int np  = wg & 1, tl = wg >> 1;
    const int b   = tl >> 6, r0 = (tl & 63) * 64, n0 = np * 128;
    const int w = tid >> 6, lane = tid & 63, lr = lane & 15, lg = lane >> 4;
    const int wr = w >> 1, wc = w & 1;

    // W glds: lane -> (row-in-8-group, pre-swizzled quarter). Involution q^(row&7).
    const int wrow8 = lane >> 3;
    const int wq    = (lane & 7) ^ wrow8;
    auto wstage = [&](int ch, int buf) {
        #pragma unroll
        for (int i = 0; i < 4; ++i) {
            const unsigned short* g =
                Wbf + (size_t)(n0 + 32 * w + 8 * i + wrow8) * DD + 64 * ch + 8 * wq;
            GLDS16(g, &U.s.wl[buf][32 * w + 8 * i][0]);
        }
    };

    // x reg-stage: thread -> (row, 16 k-floats)
    const int xrow = tid >> 2, xc4 = tid & 3;
    const float* xp = x + ((size_t)(b * TT + r0 + xrow)) * DD + 16 * xc4;
    float xr[16];
    auto xload = [&](int ch) {
        #pragma unroll
        for (int i = 0; i < 4; ++i) {
            float4 v = *(const float4*)(xp + 64 * ch + 4 * i);
            xr[4*i] = v.x; xr[4*i+1] = v.y; xr[4*i+2] = v.z; xr[4*i+3] = v.w;
        }
    };
    auto xstore = [&](int buf) {
        unsigned int pk[8];
        #pragma unroll
        for (int i = 0; i < 8; ++i)
            pk[i] = f2bf(xr[2*i]) | (f2bf(xr[2*i+1]) << 16);
        int q0 = (2 * xc4)     ^ (xrow & 7);
        int q1 = (2 * xc4 + 1) ^ (xrow & 7);
        *(u32x4*)&U.s.xl[buf][xrow][8 * q0] = (u32x4){pk[0], pk[1], pk[2], pk[3]};
        *(u32x4*)&U.s.xl[buf][xrow][8 * q1] = (u32x4){pk[4], pk[5], pk[6], pk[7]};
    };

    f32x4 acc[2][4];
    #pragma unroll
    for (int m = 0; m < 2; ++m)
        #pragma unroll
        for (int n = 0; n < 4; ++n) acc[m][n] = (f32x4){0.f, 0.f, 0.f, 0.f};

    wstage(0, 0);
    xload(0);
    xstore(0);
    __syncthreads();                          // drains glds (vmcnt 0 at barrier)

    #pragma unroll
    for (int ch = 0; ch < 4; ++ch) {
        const int buf = ch & 1;
        if (ch < 3) { wstage(ch + 1, buf ^ 1); xload(ch + 1); }
        short8 af[2][2], bfr[4][2];
        #pragma unroll
        for (int m = 0; m < 2; ++m) {
            int row = 32 * wr + 16 * m + lr;
            #pragma unroll
            for (int ks = 0; ks < 2; ++ks)
                af[m][ks] = *(const short8*)&U.s.xl[buf][row][8 * ((4 * ks + lg) ^ (lr & 7))];
        }
        #pragma unroll
        for (int n = 0; n < 4; ++n) {
            int row = 64 * wc + 16 * n + lr;
            #pragma unroll
            for (int ks = 0; ks < 2; ++ks)
                bfr[n][ks] = *(const short8*)&U.s.wl[buf][row][8 * ((4 * ks + lg) ^ (lr & 7))];
        }
        #pragma unroll
        for (int ks = 0; ks < 2; ++ks)
            #pragma unroll
            for (int m = 0; m < 2; ++m)
                #pragma unroll
                for (int n = 0; n < 4; ++n)
                    acc[m][n] = __builtin_amdgcn_mfma_f32_16x16x32_bf16(
                        af[m][ks], bfr[n][ks], acc[m][n], 0, 0, 0);
        if (ch < 3) xstore(buf ^ 1);          // T14: convert/write after MFMA
        __syncthreads();
    }

    // epilogue: z = w[t]*(acc+bias); transpose to [n][t] via T; store zw
    float wvv[2][4];
    #pragma unroll
    for (int m = 0; m < 2; ++m)
        #pragma unroll
        for (int j = 0; j < 4; ++j)
            wvv[m][j] = __expf(mask[b * TT + r0 + 32 * wr + 16 * m + 4 * lg + j] * INV_E);
    float bv[4];
    #pragma unroll
    for (int n = 0; n < 4; ++n) bv[n] = bin[n0 + 64 * wc + 16 * n + lr];

    #pragma unroll
    for (int m = 0; m < 2; ++m)
        #pragma unroll
        for (int n = 0; n < 4; ++n) {
            int col = 64 * wc + 16 * n + lr;
            int tw  = 16 * wr + 8 * m + 2 * lg;       // word index (t/2), even
            u32x2 t2;
            t2.x = f2bf((acc[m][n][0] + bv[n]) * wvv[m][0])
                 | (f2bf((acc[m][n][1] + bv[n]) * wvv[m][1]) << 16);
            t2.y = f2bf((acc[m][n][2] + bv[n]) * wvv[m][2])
                 | (f2bf((acc[m][n][3] + bv[n]) * wvv[m][3]) << 16);
            *(u32x2*)&U.T[col][tw] = t2;
        }
    __syncthreads();
    {
        int d = tid >> 1, h = tid & 1;
        unsigned short* dst = zw + ((size_t)(b * DD + n0 + d)) * TT + r0 + 32 * h;
        #pragma unroll
        for (int u = 0; u < 4; ++u)
            *(u32x4*)(dst + 8 * u) = *(const u32x4*)&U.T[d][16 * h + 4 * u];
    }
}

// ---- k2: out[i][d] = sum_t r^|i-t| * zw[d][t]; 128 i-rows x 32 d-cols/block ----
__global__ __launch_bounds__(256, 4)
void k2(const unsigned short* __restrict__ zw, float* __restrict__ out)
{
    __shared__ unsigned short zl[32][264];    // [d][t-window 256], pitch 264 (16.9 KB)

    const int tid = threadIdx.x;
    const int cpx = (int)gridDim.x >> 3;
    const int wg  = ((int)blockIdx.x & 7) * cpx + ((int)blockIdx.x >> 3);
    const int dq  = wg & 7, tl = wg >> 3;
    const int b   = tl >> 5, r0 = (tl & 31) * 128, t0 = r0 - 64, d0 = dq * 32;
    const int w = tid >> 6, lane = tid & 63, lr = lane & 15, lg = lane >> 4;

    // stage issue first (T14): 4 predicated u32x4 per thread
    const int srow = tid >> 3, spart = tid & 7;
    const unsigned short* zp = zw + ((size_t)(b * DD + d0 + srow)) * TT;
    u32x4 sv[4];
    #pragma unroll
    for (int i = 0; i < 4; ++i) {
        int tq = t0 + 32 * spart + 8 * i;
        u32x4 v = (u32x4){0u, 0u, 0u, 0u};
        if (tq >= 0 && tq < TT) v = *(const u32x4*)(zp + tq);
        sv[i] = v;
    }

    // Toeplitz A-frags in registers (128 exp2f, hides load latency)
    short8 af[2][8];
    #pragma unroll
    for (int m = 0; m < 2; ++m)
        #pragma unroll
        for (int ch = 0; ch < 8; ++ch) {
            unsigned int p[4];
            #pragma unroll
            for (int pp = 0; pp < 4; ++pp) {
                int dl0 = (32 * w + 16 * m + lr + 64) - (32 * ch + 8 * lg + 2 * pp);
                int dl1 = dl0 - 1;
                float f0 = exp2f(LOG2R * (float)((dl0 < 0) ? -dl0 : dl0));
                float f1 = exp2f(LOG2R * (float)((dl1 < 0) ? -dl1 : dl1));
                p[pp] = f2bf(f0) | (f2bf(f1) << 16);
            }
            af[m][ch] = __builtin_bit_cast(short8, (u32x4){p[0], p[1], p[2], p[3]});
        }

    #pragma unroll
    for (int i = 0; i < 4; ++i)
        *(u32x4*)&zl[srow][32 * spart + 8 * i] = sv[i];
    __syncthreads();

    f32x4 acc[2][2];
    #pragma unroll
    for (int m = 0; m < 2; ++m)
        #pragma unroll
        for (int nn = 0; nn < 2; ++nn) acc[m][nn] = (f32x4){0.f, 0.f, 0.f, 0.f};

    #pragma unroll
    for (int ch = 0; ch < 8; ++ch) {
        short8 b0 = *(const short8*)&zl[lr][8 * (4 * ch + lg)];
        short8 b1 = *(const short8*)&zl[16 + lr][8 * (4 * ch + lg)];
        acc[0][0] = __builtin_amdgcn_mfma_f32_16x16x32_bf16(af[0][ch], b0, acc[0][0], 0, 0, 0);
        acc[0][1] = __builtin_amdgcn_mfma_f32_16x16x32_bf16(af[0][ch], b1, acc[0][1], 0, 0, 0);
        acc[1][0] = __builtin_amdgcn_mfma_f32_16x16x32_bf16(af[1][ch], b0, acc[1][0], 0, 0, 0);
        acc[1][1] = __builtin_amdgcn_mfma_f32_16x16x32_bf16(af[1][ch], b1, acc[1][1], 0, 0, 0);
    }

    // C/D map: row = (lane>>4)*4+j, col = lane&15  [validated rounds 2-6]
    float* ob = out + ((size_t)(b * TT + r0 + 32 * w)) * DD + d0;
    #pragma unroll
    for (int m = 0; m < 2; ++m)
        #pragma unroll
        for (int j = 0; j < 4; ++j)
            #pragma unroll
            for (int nn = 0; nn < 2; ++nn)
                ob[(16 * m + 4 * lg + j) * DD + 16 * nn + lr] = acc[m][nn][j];
}

extern "C" void kernel_launch(void* const* d_in, const int* in_sizes, int n_in,
                              void* d_out, int out_size, void* d_ws, size_t ws_size,
                              hipStream_t stream) {
    const float* x    = (const float*)d_in[0];
    const float* mask = (const float*)d_in[1];
    const float* Win  = (const float*)d_in[2];
    const float* bin  = (const float*)d_in[3];
    float* out = (float*)d_out;

    const int nb = in_sizes[0] / (TT * DD);                    // 4 batches
    unsigned short* zwp = (unsigned short*)d_ws;               // [nb][256][4096] bf16 (8 MiB)
    unsigned short* Wbf = (unsigned short*)((char*)d_ws + (8u << 20));  // 128 KB

    hipLaunchKernelGGL(kPre, dim3(DD * DD / 1024), dim3(256), 0, stream, Win, Wbf);
    hipLaunchKernelGGL(k1, dim3(nb * 128), dim3(256), 0, stream, x, mask, Wbf, bin, zwp);
    hipLaunchKernelGGL(k2, dim3(nb * 256), dim3(256), 0, stream, zwp, out);
}

// Round 8
// 23.422 us; speedup vs baseline: 1.7162x; 1.7162x over previous
//
#include <hip/hip_runtime.h>

#define TT 4096
#define DD 256
#define BT 64
#define HW 64
#define WIN 192
#define YP 264
#define YFP 257

typedef __attribute__((ext_vector_type(8))) short short8;
typedef __attribute__((ext_vector_type(4))) float f32x4;
typedef __attribute__((ext_vector_type(2))) unsigned int u32x2;

__device__ __forceinline__ unsigned int f2bf(float f) {
    unsigned int u = __builtin_bit_cast(unsigned int, f);
    u += 0x7fffu + ((u >> 16) & 1u);          // RNE
    return u >> 16;
}
__device__ __forceinline__ float bf2f(unsigned int h) {
    unsigned int u = h << 16;
    return __builtin_bit_cast(float, u);
}

#define INV_E 0.36787944117144233f
#define RDEC  0.69220062755534635f            // exp(-1/e)

#define GLDS16(g, l) __builtin_amdgcn_global_load_lds(                         \
    (const __attribute__((address_space(1))) void*)(g),                        \
    (__attribute__((address_space(3))) void*)(l), 16, 0, 0)

// ---------------- kPre: W fp32 -> bf16 (once, 128 KB out) ----------------
__global__ __launch_bounds__(256)
void kPre(const float* __restrict__ Win, unsigned short* __restrict__ Wbf) {
    int i = ((int)blockIdx.x * 256 + (int)threadIdx.x) * 4;
    float4 v = *(const float4*)(Win + i);
    u32x2 p;
    p.x = f2bf(v.x) | (f2bf(v.y) << 16);
    p.y = f2bf(v.z) | (f2bf(v.w) << 16);
    *(u32x2*)(Wbf + i) = p;
}

// ---------------- kMain: fused conv-scan + proj GEMM, 1024 threads ----------
__global__ __launch_bounds__(1024)
void kMain(const float* __restrict__ x, const float* __restrict__ mask,
           const unsigned short* __restrict__ Wbf, const float* __restrict__ bin,
           float* __restrict__ out)
{
    __shared__ float          yF[BT][YFP];     // fwd-main partial F' (fp32, 65.8 KB)
    __shared__ unsigned short yB[BT][YP];      // (B'-v) then final y bf16 (33.8 KB)
    __shared__ unsigned short Wl[2][DD][32];   // W chunk dbuf (glds dest, 32 KB)
    __shared__ float wv[WIN], rp[WIN];
    __shared__ float cA[DD], cC[DD];           // scan carries
    __shared__ float sp[16][BT];
    __shared__ float s_l[BT];

    const int tid  = threadIdx.x;
    const int orig = blockIdx.x;
    const int wg   = (orig & 7) * 32 + (orig >> 3);   // XCD-contiguous row tiles
    const int b    = wg >> 6;
    const int r0   = (wg & 63) * BT;
    const int base = r0 - HW;

    if (tid < WIN) {
        rp[tid] = __expf(-(float)tid * INV_E);
        int j = base + tid;
        wv[tid] = (j >= 0 && j < TT) ? __expf(mask[b * TT + j] * INV_E) : 0.0f;
    }
    __syncthreads();

    const int w = tid >> 6, lane = tid & 63;
    const int lr = lane & 15, lg = lane >> 4;
    const int wr = w >> 2, wc = w & 3;

    // W stage: one glds per thread per chunk (wave w covers rows 16w..16w+15)
    const int wlrow = 16 * w + (lane >> 2);
    const int wq    = (lane & 3) ^ (wlrow & 3);       // pre-swizzled source quarter
    auto wstage = [&](int ch, int buf) {
        const unsigned short* g = Wbf + (size_t)wlrow * DD + 32 * ch + 8 * wq;
        GLDS16(g, &Wl[buf][16 * w][0]);
    };
    wstage(0, 0);                                     // flies under the whole scan

    // ---- phase 1: 4 concurrent depth-64 chains (g = tid>>8), column c ----
    {
        const int g = tid >> 8, c = tid & 255;
        const float* xc = x + (size_t)b * TT * DD + c;
        if (g == 0) {                                 // fwd halo [0,64) -> carry cA
            float f = 0.0f;
            #pragma unroll 8
            for (int t = 0; t < 64; ++t) {
                int j = base + t; j = max(j, 0);
                f = fmaf(RDEC, f, xc[(size_t)j * DD] * wv[t]);
            }
            cA[c] = f;
        } else if (g == 1) {                          // fwd main [64,128) -> F'
            float f = 0.0f;
            #pragma unroll 8
            for (int t = 64; t < 128; ++t) {
                f = fmaf(RDEC, f, xc[(size_t)(base + t) * DD] * wv[t]);
                yF[t - 64][c] = f;
            }
        } else if (g == 2) {                          // bwd halo [128,192) -> carry cC
            float bb = 0.0f;
            #pragma unroll 8
            for (int t = 191; t >= 128; --t) {
                int j = base + t; j = min(j, TT - 1);
                bb = fmaf(RDEC, bb, xc[(size_t)j * DD] * wv[t]);
            }
            cC[c] = bb;
        } else {                                      // bwd main [64,128) -> B'-v
            float bb = 0.0f;
            #pragma unroll 8
            for (int t = 127; t >= 64; --t) {
                float v = xc[(size_t)(base + t) * DD] * wv[t];
                bb = fmaf(RDEC, bb, v);
                yB[t - 64][c] = (unsigned short)f2bf(bb - v);
            }
        }
    }
    // attn row sums (bias term), 16 groups x 12 window terms
    {
        int row = tid & 63, q = tid >> 6;
        float s = 0.0f;
        #pragma unroll
        for (int tt = 0; tt < 12; ++tt) {
            int t = 12 * q + tt;
            int d = row + HW - t; d = (d < 0) ? -d : d;
            s = fmaf(rp[d], wv[t], s);
        }
        sp[q][row] = s;
    }
    __syncthreads();

    // ---- combine: y = F' + (B'-v) + r^{i+1} cA + r^{64-i} cC ----
    #pragma unroll
    for (int e = 0; e < 16; ++e) {
        int idx = (e << 10) | tid;
        int i = idx >> 8, c = idx & 255;
        float yv = yF[i][c] + bf2f(yB[i][c]) + rp[i + 1] * cA[c] + rp[64 - i] * cC[c];
        yB[i][c] = (unsigned short)f2bf(yv);
    }
    if (tid < BT) {
        float s = 0.0f;
        #pragma unroll
        for (int q = 0; q < 16; ++q) s += sp[q][tid];
        s_l[tid] = s;
    }
    __syncthreads();                                  // yB final + Wl[0] ready

    // ---- phase 2: out = y @ W^T; 16 waves, 8 K-chunks, glds double-buffer ----
    f32x4 acc[4];
    #pragma unroll
    for (int n = 0; n < 4; ++n) acc[n] = (f32x4){0.f, 0.f, 0.f, 0.f};

    #pragma unroll
    for (int ch = 0; ch < 8; ++ch) {
        const int buf = ch & 1;
        if (ch < 7) wstage(ch + 1, buf ^ 1);
        short8 af = *(const short8*)&yB[16 * wr + lr][32 * ch + 8 * lg];
        #pragma unroll
        for (int n = 0; n < 4; ++n) {
            int rn = 64 * wc + 16 * n + lr;
            short8 bf8 = *(const short8*)&Wl[buf][rn][8 * (lg ^ (rn & 3))];
            acc[n] = __builtin_amdgcn_mfma_f32_16x16x32_bf16(af, bf8, acc[n], 0, 0, 0);
        }
        __syncthreads();                              // drains glds for next chunk
    }

    // ---- epilogue (C/D map: row=(lane>>4)*4+j, col=lane&15; validated) ----
    float bcol[4];
    #pragma unroll
    for (int n = 0; n < 4; ++n) bcol[n] = bin[64 * wc + 16 * n + lr];
    float* ob = out + ((size_t)(b * TT + r0)) * DD;
    #pragma unroll
    for (int n = 0; n < 4; ++n)
        #pragma unroll
        for (int j = 0; j < 4; ++j) {
            int i = 16 * wr + 4 * lg + j;
            ob[(size_t)i * DD + 64 * wc + 16 * n + lr] = acc[n][j] + s_l[i] * bcol[n];
        }
}

extern "C" void kernel_launch(void* const* d_in, const int* in_sizes, int n_in,
                              void* d_out, int out_size, void* d_ws, size_t ws_size,
                              hipStream_t stream) {
    const float* x    = (const float*)d_in[0];
    const float* mask = (const float*)d_in[1];
    const float* Win  = (const float*)d_in[2];
    const float* bin  = (const float*)d_in[3];
    float* out = (float*)d_out;

    const int nb = in_sizes[0] / (TT * DD);           // 4 batches
    unsigned short* Wbf = (unsigned short*)d_ws;      // 128 KB bf16 W

    hipLaunchKernelGGL(kPre, dim3(DD * DD / 1024), dim3(256), 0, stream, Win, Wbf);
    hipLaunchKernelGGL(kMain, dim3(nb * (TT / BT)), dim3(1024), 0, stream,
                       x, mask, Wbf, bin, out);
}

// Round 9
// 22.757 us; speedup vs baseline: 1.7664x; 1.0292x over previous
//
#include <hip/hip_runtime.h>

#define TT 4096
#define DD 256
#define BT 64
#define HW 32
#define WIN 128
#define YP 264
#define YFP 257

typedef __attribute__((ext_vector_type(8))) short short8;
typedef __attribute__((ext_vector_type(4))) float f32x4;
typedef __attribute__((ext_vector_type(2))) unsigned int u32x2;

__device__ __forceinline__ unsigned int f2bf(float f) {
    unsigned int u = __builtin_bit_cast(unsigned int, f);
    u += 0x7fffu + ((u >> 16) & 1u);          // RNE
    return u >> 16;
}
__device__ __forceinline__ float bf2f(unsigned int h) {
    unsigned int u = h << 16;
    return __builtin_bit_cast(float, u);
}

#define INV_E 0.36787944117144233f
#define RDEC  0.69220062755534635f            // exp(-1/e)

#define GLDS16(g, l) __builtin_amdgcn_global_load_lds(                         \
    (const __attribute__((address_space(1))) void*)(g),                        \
    (__attribute__((address_space(3))) void*)(l), 16, 0, 0)

// ---------------- kPre: W fp32 -> bf16 (once, 128 KB out) ----------------
__global__ __launch_bounds__(256)
void kPre(const float* __restrict__ Win, unsigned short* __restrict__ Wbf) {
    int i = ((int)blockIdx.x * 256 + (int)threadIdx.x) * 4;
    float4 v = *(const float4*)(Win + i);
    u32x2 p;
    p.x = f2bf(v.x) | (f2bf(v.y) << 16);
    p.y = f2bf(v.z) | (f2bf(v.w) << 16);
    *(u32x2*)(Wbf + i) = p;
}

// ---------------- kMain: fused conv-scan + proj GEMM, 1024 threads ----------
__global__ __launch_bounds__(1024)
void kMain(const float* __restrict__ x, const float* __restrict__ mask,
           const unsigned short* __restrict__ Wbf, const float* __restrict__ bin,
           float* __restrict__ out)
{
    __shared__ float          yF[BT][YFP];     // fwd partial F (fp32, 65.8 KB)
    __shared__ unsigned short yB[BT][YP];      // (B-v) then final y bf16 (33.8 KB)
    __shared__ unsigned short Wl[2][DD][32];   // W chunk dbuf (glds dest, 32 KB)
    __shared__ float wv[WIN], rp[WIN];
    __shared__ float cA[DD], cC[DD];           // scan carries (fwd@47, bwd@80)
    __shared__ float sp[16][BT];
    __shared__ float s_l[BT];

    const int tid  = threadIdx.x;
    const int orig = blockIdx.x;
    const int wg   = (orig & 7) * 32 + (orig >> 3);   // XCD-contiguous row tiles
    const int b    = wg >> 6;
    const int r0   = (wg & 63) * BT;
    const int base = r0 - HW;

    if (tid < WIN) {
        rp[tid] = __expf(-(float)tid * INV_E);
        int j = base + tid;
        wv[tid] = (j >= 0 && j < TT) ? __expf(mask[b * TT + j] * INV_E) : 0.0f;
    }
    __syncthreads();

    const int w = tid >> 6, lane = tid & 63;
    const int lr = lane & 15, lg = lane >> 4;
    const int wr = w >> 2, wc = w & 3;

    // W stage: one glds per thread per chunk (wave w covers rows 16w..16w+15)
    const int wlrow = 16 * w + (lane >> 2);
    const int wq    = (lane & 3) ^ (wlrow & 3);       // pre-swizzled source quarter
    auto wstage = [&](int ch, int buf) {
        const unsigned short* g = Wbf + (size_t)wlrow * DD + 32 * ch + 8 * wq;
        GLDS16(g, &Wl[buf][16 * w][0]);
    };
    wstage(0, 0);                                     // flies under the whole scan

    // ---- phase 1: 4 balanced depth-48 chains (g = tid>>8), column c ----
    // window rows w in [0,128), main rows w in [32,96), output i = w-32.
    {
        const int g = tid >> 8, c = tid & 255;
        const float* xc = x + (size_t)b * TT * DD + c;
        if (g == 0) {                                 // fwd [0,48): store i<16, carry cA@47
            float f = 0.0f;
            #pragma unroll 8
            for (int t = 0; t < 32; ++t) {
                int j = base + t; j = max(j, 0);
                f = fmaf(RDEC, f, xc[(size_t)j * DD] * wv[t]);
            }
            #pragma unroll 8
            for (int t = 32; t < 48; ++t) {
                f = fmaf(RDEC, f, xc[(size_t)(base + t) * DD] * wv[t]);
                yF[t - 32][c] = f;
            }
            cA[c] = f;
        } else if (g == 1) {                          // fwd [48,96): store i in [16,64)
            float f = 0.0f;
            #pragma unroll 8
            for (int t = 48; t < 96; ++t) {
                f = fmaf(RDEC, f, xc[(size_t)(base + t) * DD] * wv[t]);
                yF[t - 32][c] = f;
            }
        } else if (g == 2) {                          // bwd [80,128): store i>=48, carry cC@80
            float bb = 0.0f;
            #pragma unroll 8
            for (int t = 127; t >= 96; --t) {
                int j = base + t; j = min(j, TT - 1);
                bb = fmaf(RDEC, bb, xc[(size_t)j * DD] * wv[t]);
            }
            #pragma unroll 8
            for (int t = 95; t >= 80; --t) {
                float v = xc[(size_t)(base + t) * DD] * wv[t];
                bb = fmaf(RDEC, bb, v);
                yB[t - 32][c] = (unsigned short)f2bf(bb - v);
            }
            cC[c] = bb;
        } else {                                      // bwd [32,80): store i in [0,48)
            float bb = 0.0f;
            #pragma unroll 8
            for (int t = 79; t >= 32; --t) {
                float v = xc[(size_t)(base + t) * DD] * wv[t];
                bb = fmaf(RDEC, bb, v);
                yB[t - 32][c] = (unsigned short)f2bf(bb - v);
            }
        }
    }
    // attn row sums (bias term): 16 groups x 8 window terms
    {
        int row = tid & 63, q = tid >> 6;
        float s = 0.0f;
        #pragma unroll
        for (int tt = 0; tt < 8; ++tt) {
            int t = 8 * q + tt;
            int d = row + HW - t; d = (d < 0) ? -d : d;
            s = fmaf(rp[d], wv[t], s);
        }
        sp[q][row] = s;
    }
    __syncthreads();

    // ---- combine: y = F + (B-v) + [i>=16] rp[i-15]*cA + [i<48] rp[48-i]*cC ----
    #pragma unroll
    for (int e = 0; e < 16; ++e) {
        int idx = (e << 10) | tid;
        int i = idx >> 8, c = idx & 255;
        float yv = yF[i][c] + bf2f(yB[i][c]);
        if (i >= 16) yv += rp[i - 15] * cA[c];
        if (i < 48)  yv += rp[48 - i] * cC[c];
        yB[i][c] = (unsigned short)f2bf(yv);
    }
    if (tid < BT) {
        float s = 0.0f;
        #pragma unroll
        for (int q = 0; q < 16; ++q) s += sp[q][tid];
        s_l[tid] = s;
    }
    __syncthreads();                                  // yB final + Wl[0] ready

    // ---- phase 2: out = y @ W^T; 16 waves, 8 K-chunks, glds double-buffer ----
    f32x4 acc[4];
    #pragma unroll
    for (int n = 0; n < 4; ++n) acc[n] = (f32x4){0.f, 0.f, 0.f, 0.f};

    #pragma unroll
    for (int ch = 0; ch < 8; ++ch) {
        const int buf = ch & 1;
        if (ch < 7) wstage(ch + 1, buf ^ 1);
        short8 af = *(const short8*)&yB[16 * wr + lr][32 * ch + 8 * lg];
        #pragma unroll
        for (int n = 0; n < 4; ++n) {
            int rn = 64 * wc + 16 * n + lr;
            short8 bf8 = *(const short8*)&Wl[buf][rn][8 * (lg ^ (rn & 3))];
            acc[n] = __builtin_amdgcn_mfma_f32_16x16x32_bf16(af, bf8, acc[n], 0, 0, 0);
        }
        __syncthreads();                              // drains glds for next chunk
    }

    // ---- epilogue (C/D map: row=(lane>>4)*4+j, col=lane&15; validated) ----
    float bcol[4];
    #pragma unroll
    for (int n = 0; n < 4; ++n) bcol[n] = bin[64 * wc + 16 * n + lr];
    float* ob = out + ((size_t)(b * TT + r0)) * DD;
    #pragma unroll
    for (int n = 0; n < 4; ++n)
        #pragma unroll
        for (int j = 0; j < 4; ++j) {
            int i = 16 * wr + 4 * lg + j;
            ob[(size_t)i * DD + 64 * wc + 16 * n + lr] = acc[n][j] + s_l[i] * bcol[n];
        }
}

extern "C" void kernel_launch(void* const* d_in, const int* in_sizes, int n_in,
                              void* d_out, int out_size, void* d_ws, size_t ws_size,
                              hipStream_t stream) {
    const float* x    = (const float*)d_in[0];
    const float* mask = (const float*)d_in[1];
    const float* Win  = (const float*)d_in[2];
    const float* bin  = (const float*)d_in[3];
    float* out = (float*)d_out;

    const int nb = in_sizes[0] / (TT * DD);           // 4 batches
    unsigned short* Wbf = (unsigned short*)d_ws;      // 128 KB bf16 W

    hipLaunchKernelGGL(kPre, dim3(DD * DD / 1024), dim3(256), 0, stream, Win, Wbf);
    hipLaunchKernelGGL(kMain, dim3(nb * (TT / BT)), dim3(1024), 0, stream,
                       x, mask, Wbf, bin, out);
}